// Round 1
// baseline (2416.398 us; speedup 1.0000x reference)
//
#include <hip/hip_runtime.h>
#include <hip/hip_fp16.h>
#include <stdint.h>

#define T_STEPS 1024
#define HDIM    128
#define NT      256   // 4 waves/CU, 1 wave/SIMD -> 512-reg unified budget/wave

// ---- packed f16-pair types --------------------------------------------------
typedef _Float16 v2h  __attribute__((ext_vector_type(2)));
typedef unsigned int u16x __attribute__((ext_vector_type(16)));  // 16 f16-pairs

union HU { uint32_t u; v2h v; };

// d = a0*b0 + a1*b1 + c  (f16 inputs, f32 accumulate) -> v_dot2_f32_f16
__device__ __forceinline__ float dot2h(uint32_t a, uint32_t b, float c) {
    HU ua, ub; ua.u = a; ub.u = b;
    return __builtin_amdgcn_fdot2(ua.v, ub.v, c, false);
}

__device__ __forceinline__ uint32_t packh2f(float2 e) {
    return (uint32_t)__half_as_ushort(__float2half_rn(e.x)) |
           ((uint32_t)__half_as_ushort(__float2half_rn(e.y)) << 16);
}
__device__ __forceinline__ uint16_t f2h(float f) {
    return __half_as_ushort(__float2half_rn(f));
}
__device__ __forceinline__ float sigmoidf_(float x) {
    return 1.0f / (1.0f + __expf(-x));
}
__device__ __forceinline__ float tanhf_(float x) {
    return 1.0f - 2.0f / (__expf(2.0f * x) + 1.0f);
}

// Scheduling fence: caps live LDS-read temps at one 3-buffer rotation.
// Without it the pre-RA scheduler hoists all ds_reads -> 350 live regs ->
// the allocator spills the loop-invariant weights to scratch (the 71 MB
// WRITE_SIZE / 35 TB/s L2 stream that pinned the previous version at 2 ms).
#define SB() __builtin_amdgcn_sched_barrier(0)

// Load quarter q (16 f16-pairs = 32 floats) of a weight row into a named
// ext-vector SSA value. Constant indices only — no alloca is ever created.
#define SETW(W, rowptr, q) do {                                            \
    const float2* _r = ((const float2*)(rowptr)) + 16 * (q);               \
    W[0]  = packh2f(_r[0]);  W[1]  = packh2f(_r[1]);                       \
    W[2]  = packh2f(_r[2]);  W[3]  = packh2f(_r[3]);                       \
    W[4]  = packh2f(_r[4]);  W[5]  = packh2f(_r[5]);                       \
    W[6]  = packh2f(_r[6]);  W[7]  = packh2f(_r[7]);                       \
    W[8]  = packh2f(_r[8]);  W[9]  = packh2f(_r[9]);                       \
    W[10] = packh2f(_r[10]); W[11] = packh2f(_r[11]);                      \
    W[12] = packh2f(_r[12]); W[13] = packh2f(_r[13]);                      \
    W[14] = packh2f(_r[14]); W[15] = packh2f(_r[15]);                      \
} while (0)

// Load one h-quarter (4 x uint4 = 16 f16-pairs) into a named register buffer.
#define LOADQ(P0, P1, P2, P3, Hv, q) do {                                  \
    P0 = (Hv)[4*(q)+0]; P1 = (Hv)[4*(q)+1];                                \
    P2 = (Hv)[4*(q)+2]; P3 = (Hv)[4*(q)+3];                                \
} while (0)

// 16 dot2s of one weight-quarter vs one buffered h-quarter.
// Split into two 8-deep chains (accA/accB) -> with two rows per thread we
// get 4 independent chains per segment: dep-latency fully covered.
#define DOTQ(W, P0, P1, P2, P3, accA, accB) do {                           \
    accA = dot2h(W[0],  P0.x, accA); accA = dot2h(W[1],  P0.y, accA);      \
    accA = dot2h(W[2],  P0.z, accA); accA = dot2h(W[3],  P0.w, accA);      \
    accA = dot2h(W[4],  P1.x, accA); accA = dot2h(W[5],  P1.y, accA);      \
    accA = dot2h(W[6],  P1.z, accA); accA = dot2h(W[7],  P1.w, accA);      \
    accB = dot2h(W[8],  P2.x, accB); accB = dot2h(W[9],  P2.y, accB);      \
    accB = dot2h(W[10], P2.z, accB); accB = dot2h(W[11], P2.w, accB);      \
    accB = dot2h(W[12], P3.x, accB); accB = dot2h(W[13], P3.y, accB);      \
    accB = dot2h(W[14], P3.z, accB); accB = dot2h(W[15], P3.w, accB);      \
} while (0)

// 1 wave/SIMD: unified VGPR+AGPR budget 512/wave. Demand: 384 weight dwords
// + 48 buffer dwords + ~25 misc ≈ 460 — fits with headroom (spill-free
// verified territory is <=450..512).
__global__ __launch_bounds__(NT, 1) void lstm_persistent(
    const float* __restrict__ x,
    const float* __restrict__ W_ih1, const float* __restrict__ W_hh1,
    const float* __restrict__ b_ih1, const float* __restrict__ b_hh1,
    const float* __restrict__ W_ih2, const float* __restrict__ W_hh2,
    const float* __restrict__ b_ih2, const float* __restrict__ b_hh2,
    const float* __restrict__ W_out, const float* __restrict__ b_out,
    float* __restrict__ out)
{
    const int b   = blockIdx.x;    // sample
    const int tid = threadIdx.x;   // 0..255; owns gate rows tid and tid+256
    const int rB  = tid + 256;

    __shared__ __align__(16) uint32_t h1p[HDIM / 2];  // h1 as f16 pairs
    __shared__ __align__(16) uint32_t h2p[HDIM / 2];  // h2 as f16 pairs
    __shared__ float gact[2 * NT];                    // 512 activated gates
    __shared__ float h2f[HDIM];                       // fp32 h2 for output dot

    // ---- one-time: this thread's 6 weight rows as 24 named vector values
    u16x w1A0, w1A1, w1A2, w1A3, w1B0, w1B1, w1B2, w1B3;  // W_hh1 rows tid, tid+256
    u16x w2A0, w2A1, w2A2, w2A3, w2B0, w2B1, w2B2, w2B3;  // W_ih2
    u16x w3A0, w3A1, w3A2, w3A3, w3B0, w3B1, w3B2, w3B3;  // W_hh2
    {
        const float* r;
        r = W_hh1 + tid * HDIM; SETW(w1A0,r,0); SETW(w1A1,r,1); SETW(w1A2,r,2); SETW(w1A3,r,3);
        r = W_hh1 + rB  * HDIM; SETW(w1B0,r,0); SETW(w1B1,r,1); SETW(w1B2,r,2); SETW(w1B3,r,3);
        r = W_ih2 + tid * HDIM; SETW(w2A0,r,0); SETW(w2A1,r,1); SETW(w2A2,r,2); SETW(w2A3,r,3);
        r = W_ih2 + rB  * HDIM; SETW(w2B0,r,0); SETW(w2B1,r,1); SETW(w2B2,r,2); SETW(w2B3,r,3);
        r = W_hh2 + tid * HDIM; SETW(w3A0,r,0); SETW(w3A1,r,1); SETW(w3A2,r,2); SETW(w3A3,r,3);
        r = W_hh2 + rB  * HDIM; SETW(w3B0,r,0); SETW(w3B1,r,1); SETW(w3B2,r,2); SETW(w3B3,r,3);
    }
    const float bias1A = b_ih1[tid] + b_hh1[tid];
    const float bias1B = b_ih1[rB]  + b_hh1[rB];
    const float bias2A = b_ih2[tid] + b_hh2[tid];
    const float bias2B = b_ih2[rB]  + b_hh2[rB];
    const float wih1A  = W_ih1[tid];
    const float wih1B  = W_ih1[rB];
    float wo0 = 0.f, wo1 = 0.f;
    if (tid < 64) { wo0 = W_out[tid]; wo1 = W_out[tid + 64]; }
    const float bo = b_out[0];

    float c1 = 0.f, c2 = 0.f;       // live in threads 0..127

    if (tid < HDIM / 2) { h1p[tid] = 0u; h2p[tid] = 0u; }
    __syncthreads();

    const uint4* Hv1 = (const uint4*)h1p;
    const uint4* Hv2 = (const uint4*)h2p;

    const float* xb = x + b * T_STEPS;
    float*       ob = out + b * T_STEPS;
    float x_cur = xb[0];

    // 3 rotating h-quarter buffers, always loaded 2 segments ahead of use.
    uint4 A0, A1, A2, A3, B0, B1, B2, B3, C0, C1, C2, C3;
    LOADQ(A0, A1, A2, A3, Hv1, 0);
    LOADQ(B0, B1, B2, B3, Hv1, 1);

    for (int t = 0; t < T_STEPS; t++) {
        float x_nxt = xb[(t + 1 < T_STEPS) ? (t + 1) : t];

        // ---------- phase 1: layer-1 gate preactivations, rows tid & tid+256
        float aA = fmaf(x_cur, wih1A, bias1A), aB = 0.f;   // row tid   (i/f)
        float bA = fmaf(x_cur, wih1B, bias1B), bB = 0.f;   // row tid+256 (g/o)
        LOADQ(C0, C1, C2, C3, Hv1, 2);
        DOTQ(w1A0, A0, A1, A2, A3, aA, aB);
        DOTQ(w1B0, A0, A1, A2, A3, bA, bB); SB();
        LOADQ(A0, A1, A2, A3, Hv1, 3);
        DOTQ(w1A1, B0, B1, B2, B3, aA, aB);
        DOTQ(w1B1, B0, B1, B2, B3, bA, bB); SB();
        LOADQ(B0, B1, B2, B3, Hv2, 0);          // prefetch h2 q0 for phase 2
        DOTQ(w1A2, C0, C1, C2, C3, aA, aB);
        DOTQ(w1B2, C0, C1, C2, C3, bA, bB); SB();
        LOADQ(C0, C1, C2, C3, Hv2, 1);          // prefetch h2 q1 for phase 2
        DOTQ(w1A3, A0, A1, A2, A3, aA, aB);
        DOTQ(w1B3, A0, A1, A2, A3, bA, bB);
        float g1A = aA + aB, g1B = bA + bB;
        gact[tid] = sigmoidf_(g1A);                          // rows 0..255: i,f
        gact[rB]  = (tid < 128) ? tanhf_(g1B) : sigmoidf_(g1B); // 256..383 g, 384..511 o
        __syncthreads();   // barrier 1

        // ---------- layer-1 state update (threads 0..127, c1 in registers)
        if (tid < HDIM) {
            float gi = gact[tid], gf = gact[tid + 128];
            float gg = gact[tid + 256], go = gact[tid + 384];
            c1 = fmaf(gf, c1, gi * gg);
            float h1 = go * tanhf_(c1);
            ((uint16_t*)h1p)[tid] = f2h(h1);
        }
        __syncthreads();   // barrier 2

        // ---------- phase 2: layer-2 gates = W_ih2·h1new + W_hh2·h2old
        // Start on the h2 (old, prefetched) quarters while h1new loads fly.
        float sA = bias2A, sB = 0.f;     // row tid
        float uA = bias2B, uB = 0.f;     // row tid+256
        LOADQ(A0, A1, A2, A3, Hv1, 0); SB();
        DOTQ(w3A0, B0, B1, B2, B3, sA, sB);
        DOTQ(w3B0, B0, B1, B2, B3, uA, uB); SB();
        LOADQ(B0, B1, B2, B3, Hv1, 1);
        DOTQ(w3A1, C0, C1, C2, C3, sA, sB);
        DOTQ(w3B1, C0, C1, C2, C3, uA, uB); SB();
        LOADQ(C0, C1, C2, C3, Hv2, 2);
        DOTQ(w2A0, A0, A1, A2, A3, sA, sB);
        DOTQ(w2B0, A0, A1, A2, A3, uA, uB); SB();
        LOADQ(A0, A1, A2, A3, Hv1, 2);
        DOTQ(w2A1, B0, B1, B2, B3, sA, sB);
        DOTQ(w2B1, B0, B1, B2, B3, uA, uB); SB();
        LOADQ(B0, B1, B2, B3, Hv2, 3);
        DOTQ(w3A2, C0, C1, C2, C3, sA, sB);
        DOTQ(w3B2, C0, C1, C2, C3, uA, uB); SB();
        LOADQ(C0, C1, C2, C3, Hv1, 3);
        DOTQ(w2A2, A0, A1, A2, A3, sA, sB);
        DOTQ(w2B2, A0, A1, A2, A3, uA, uB); SB();
        DOTQ(w3A3, B0, B1, B2, B3, sA, sB);
        DOTQ(w3B3, B0, B1, B2, B3, uA, uB); SB();
        DOTQ(w2A3, C0, C1, C2, C3, sA, sB);
        DOTQ(w2B3, C0, C1, C2, C3, uA, uB);
        float g2A = sA + sB, g2B = uA + uB;
        gact[tid] = sigmoidf_(g2A);
        gact[rB]  = (tid < 128) ? tanhf_(g2B) : sigmoidf_(g2B);
        __syncthreads();   // barrier 3

        // ---------- layer-2 state update
        if (tid < HDIM) {
            float gi = gact[tid], gf = gact[tid + 128];
            float gg = gact[tid + 256], go = gact[tid + 384];
            c2 = fmaf(gf, c2, gi * gg);
            float h2 = go * tanhf_(c2);
            ((uint16_t*)h2p)[tid] = f2h(h2);
            h2f[tid] = h2;
        }
        __syncthreads();   // barrier 4

        // ---------- output: out[b,t] = W_out . h2 + b_out   (wave 0 only;
        // other waves run ahead into the next-step prefetch + phase 1)
        if (tid < 64) {
            float p = fmaf(wo0, h2f[tid], wo1 * h2f[tid + 64]);
#pragma unroll
            for (int off = 32; off > 0; off >>= 1)
                p += __shfl_down(p, off, 64);
            if (tid == 0) ob[t] = p + bo;
        }

        // prefetch h1 (written this step, stable until next update1) for
        // next iteration's phase 1 — latency hides under the output phase.
        LOADQ(A0, A1, A2, A3, Hv1, 0);
        LOADQ(B0, B1, B2, B3, Hv1, 1);
        x_cur = x_nxt;
    }
}

extern "C" void kernel_launch(void* const* d_in, const int* in_sizes, int n_in,
                              void* d_out, int out_size, void* d_ws, size_t ws_size,
                              hipStream_t stream) {
    const float* x     = (const float*)d_in[0];
    const float* W_ih1 = (const float*)d_in[1];
    const float* W_hh1 = (const float*)d_in[2];
    const float* b_ih1 = (const float*)d_in[3];
    const float* b_hh1 = (const float*)d_in[4];
    const float* W_ih2 = (const float*)d_in[5];
    const float* W_hh2 = (const float*)d_in[6];
    const float* b_ih2 = (const float*)d_in[7];
    const float* b_hh2 = (const float*)d_in[8];
    const float* W_out = (const float*)d_in[9];
    const float* b_out = (const float*)d_in[10];
    float* out = (float*)d_out;

    const int B = in_sizes[0] / T_STEPS;   // 256
    hipLaunchKernelGGL(lstm_persistent, dim3(B), dim3(NT), 0, stream,
                       x, W_ih1, W_hh1, b_ih1, b_hh1,
                       W_ih2, W_hh2, b_ih2, b_hh2, W_out, b_out, out);
}

// Round 2
// 2084.394 us; speedup vs baseline: 1.1593x; 1.1593x over previous
//
#include <hip/hip_runtime.h>
#include <hip/hip_fp16.h>
#include <stdint.h>

#define T_STEPS 1024
#define HDIM    128
#define NT      512   // one gate row per thread
#define WROW    17    // uint4 per LDS weight row: 16 data + 1 pad (bank stride 4)

// ---- packed f16-pair types --------------------------------------------------
typedef _Float16 v2h  __attribute__((ext_vector_type(2)));
typedef unsigned int u16x __attribute__((ext_vector_type(16)));  // 16 f16-pairs

union HU { uint32_t u; v2h v; };

// d = a0*b0 + a1*b1 + c  (f16 inputs, f32 accumulate) -> v_dot2_f32_f16
__device__ __forceinline__ float dot2h(uint32_t a, uint32_t b, float c) {
    HU ua, ub; ua.u = a; ub.u = b;
    return __builtin_amdgcn_fdot2(ua.v, ub.v, c, false);
}

__device__ __forceinline__ uint32_t packh2f(float2 e) {
    return (uint32_t)__half_as_ushort(__float2half_rn(e.x)) |
           ((uint32_t)__half_as_ushort(__float2half_rn(e.y)) << 16);
}
__device__ __forceinline__ uint16_t f2h(float f) {
    return __half_as_ushort(__float2half_rn(f));
}
__device__ __forceinline__ float sigmoidf_(float x) {
    return 1.0f / (1.0f + __expf(-x));
}
__device__ __forceinline__ float tanhf_(float x) {
    return 1.0f - 2.0f / (__expf(2.0f * x) + 1.0f);
}

// Scheduling fence. Caps how many LDS-read temps the pre-RA scheduler can
// keep live at once. Peak register demand must stay <= ~220 addressable
// VGPRs (gfx950 non-MFMA cap is 256) or the allocator spills the
// loop-invariant weights to scratch -> 71 MB WRITE_SIZE + L2-bound reload
// stream at ~5000 cyc/step (the 2 ms plateau of rounds 0/1).
#define SB() __builtin_amdgcn_sched_barrier(0)

// Load quarter q (16 f16-pairs = 32 floats) of a weight row into a named
// ext-vector SSA value. Constant indices only — no alloca is ever created.
#define SETW(W, rowptr, q) do {                                            \
    const float2* _r = ((const float2*)(rowptr)) + 16 * (q);               \
    W[0]  = packh2f(_r[0]);  W[1]  = packh2f(_r[1]);                       \
    W[2]  = packh2f(_r[2]);  W[3]  = packh2f(_r[3]);                       \
    W[4]  = packh2f(_r[4]);  W[5]  = packh2f(_r[5]);                       \
    W[6]  = packh2f(_r[6]);  W[7]  = packh2f(_r[7]);                       \
    W[8]  = packh2f(_r[8]);  W[9]  = packh2f(_r[9]);                       \
    W[10] = packh2f(_r[10]); W[11] = packh2f(_r[11]);                      \
    W[12] = packh2f(_r[12]); W[13] = packh2f(_r[13]);                      \
    W[14] = packh2f(_r[14]); W[15] = packh2f(_r[15]);                      \
} while (0)

// 16 dot2s of one register weight-quarter vs h pairs [32q, 32q+32) from LDS
// (broadcast reads — all lanes same address, conflict-free).
#define DOT_Q(W, Hv, q, acc) do {                                          \
    uint4 _p0 = (Hv)[4*(q)+0], _p1 = (Hv)[4*(q)+1];                        \
    uint4 _p2 = (Hv)[4*(q)+2], _p3 = (Hv)[4*(q)+3];                        \
    acc = dot2h(W[0],  _p0.x, acc); acc = dot2h(W[1],  _p0.y, acc);        \
    acc = dot2h(W[2],  _p0.z, acc); acc = dot2h(W[3],  _p0.w, acc);        \
    acc = dot2h(W[4],  _p1.x, acc); acc = dot2h(W[5],  _p1.y, acc);        \
    acc = dot2h(W[6],  _p1.z, acc); acc = dot2h(W[7],  _p1.w, acc);        \
    acc = dot2h(W[8],  _p2.x, acc); acc = dot2h(W[9],  _p2.y, acc);        \
    acc = dot2h(W[10], _p2.z, acc); acc = dot2h(W[11], _p2.w, acc);        \
    acc = dot2h(W[12], _p3.x, acc); acc = dot2h(W[13], _p3.y, acc);        \
    acc = dot2h(W[14], _p3.z, acc); acc = dot2h(W[15], _p3.w, acc);        \
} while (0)

// Load W_hh2 LDS quarter q of this thread's row into 4 named uint4s.
// Row stride = WROW uint4 = 68 dwords -> bank stride 4: lanes r..r+7 cover
// all 32 banks, lanes r+8..r+15 alias 2-way (free per m136).
#define LOADW(U0, U1, U2, U3, Wv, base, q) do {                            \
    U0 = (Wv)[(base) + 4*(q) + 0]; U1 = (Wv)[(base) + 4*(q) + 1];          \
    U2 = (Wv)[(base) + 4*(q) + 2]; U3 = (Wv)[(base) + 4*(q) + 3];          \
} while (0)

#define LOADH(P0, P1, P2, P3, Hv, q) do {                                  \
    P0 = (Hv)[4*(q)+0]; P1 = (Hv)[4*(q)+1];                                \
    P2 = (Hv)[4*(q)+2]; P3 = (Hv)[4*(q)+3];                                \
} while (0)

// 16 dot2s: LDS weight quarter (U0..U3) vs h quarter (P0..P3), 2 acc chains.
#define DOTW(U0, U1, U2, U3, P0, P1, P2, P3, accA, accB) do {              \
    accA = dot2h(U0.x, P0.x, accA); accA = dot2h(U0.y, P0.y, accA);        \
    accA = dot2h(U0.z, P0.z, accA); accA = dot2h(U0.w, P0.w, accA);        \
    accA = dot2h(U1.x, P1.x, accA); accA = dot2h(U1.y, P1.y, accA);        \
    accA = dot2h(U1.z, P1.z, accA); accA = dot2h(U1.w, P1.w, accA);        \
    accB = dot2h(U2.x, P2.x, accB); accB = dot2h(U2.y, P2.y, accB);        \
    accB = dot2h(U2.z, P2.z, accB); accB = dot2h(U2.w, P2.w, accB);        \
    accB = dot2h(U3.x, P3.x, accB); accB = dot2h(U3.y, P3.y, accB);        \
    accB = dot2h(U3.z, P3.z, accB); accB = dot2h(U3.w, P3.w, accB);        \
} while (0)

// LDS (139 KB) pins occupancy to 1 block/CU = 2 waves/SIMD, so no register
// cap is needed from launch bounds: min-1-wave gives the allocator the full
// budget (round 1 showed this yields the full 256 addressable VGPRs).
__global__ __launch_bounds__(NT, 1) void lstm_persistent(
    const float* __restrict__ x,
    const float* __restrict__ W_ih1, const float* __restrict__ W_hh1,
    const float* __restrict__ b_ih1, const float* __restrict__ b_hh1,
    const float* __restrict__ W_ih2, const float* __restrict__ W_hh2,
    const float* __restrict__ b_ih2, const float* __restrict__ b_hh2,
    const float* __restrict__ W_out, const float* __restrict__ b_out,
    float* __restrict__ out)
{
    const int b   = blockIdx.x;    // sample
    const int tid = threadIdx.x;   // gate row 0..511

    __shared__ __align__(16) uint4    wlds[NT * WROW];   // W_hh2 f16, padded
    __shared__ __align__(16) uint32_t h1p[HDIM / 2];     // h1 as f16 pairs
    __shared__ __align__(16) uint32_t h2p[HDIM / 2];     // h2 as f16 pairs
    __shared__ float gact[NT];                           // activated gates
    __shared__ float h2f[HDIM];                          // fp32 h2 for output

    // ---- one-time: W_hh1/W_ih2 rows in registers (128 dwords, 8 named SSA)
    u16x w1a, w1b, w1c, w1d, w2a, w2b, w2c, w2d;
    {
        const float* r1 = W_hh1 + tid * HDIM;
        const float* r2 = W_ih2 + tid * HDIM;
        SETW(w1a, r1, 0); SETW(w1b, r1, 1); SETW(w1c, r1, 2); SETW(w1d, r1, 3);
        SETW(w2a, r2, 0); SETW(w2b, r2, 1); SETW(w2c, r2, 2); SETW(w2d, r2, 3);
    }
    // ---- one-time: W_hh2 row tid -> LDS (f16 pairs, padded row)
    {
        const float2* r3 = (const float2*)(W_hh2 + tid * HDIM);
        uint4* wv = wlds + tid * WROW;
#pragma unroll
        for (int j = 0; j < 16; ++j) {
            wv[j] = make_uint4(packh2f(r3[4*j+0]), packh2f(r3[4*j+1]),
                               packh2f(r3[4*j+2]), packh2f(r3[4*j+3]));
        }
    }
    const float bias1 = b_ih1[tid] + b_hh1[tid];
    const float bias2 = b_ih2[tid] + b_hh2[tid];
    const float wih1  = W_ih1[tid];
    const int   sec   = tid >> 7;   // 0:i 1:f 2:g 3:o
    float wo0 = 0.f, wo1 = 0.f;
    if (tid < 64) { wo0 = W_out[tid]; wo1 = W_out[tid + 64]; }
    const float bo = b_out[0];

    float c1 = 0.f, c2 = 0.f;       // live in threads 0..127

    if (tid < HDIM / 2) { h1p[tid] = 0u; h2p[tid] = 0u; }
    __syncthreads();

    const uint4* Hv1 = (const uint4*)h1p;
    const uint4* Hv2 = (const uint4*)h2p;
    const uint4* Wv  = (const uint4*)wlds;
    const int    wbase = tid * WROW;

    const float* xb = x + b * T_STEPS;
    float*       ob = out + b * T_STEPS;
    float x_cur = xb[0];

    for (int t = 0; t < T_STEPS; t++) {
        float x_nxt = xb[(t + 1 < T_STEPS) ? (t + 1) : t];

        // ---------- phase 1: layer-1 gate preactivation (row tid, reg W)
        float aA = fmaf(x_cur, wih1, bias1), aB = 0.f;
        DOT_Q(w1a, Hv1, 0, aA); DOT_Q(w1b, Hv1, 1, aB); SB();
        DOT_Q(w1c, Hv1, 2, aA); DOT_Q(w1d, Hv1, 3, aB);
        float a1 = aA + aB;
        gact[tid] = (sec == 2) ? tanhf_(a1) : sigmoidf_(a1);
        __syncthreads();   // barrier 1

        // ---------- layer-1 state update (threads 0..127, c1 in registers)
        if (tid < HDIM) {
            float gi = gact[tid], gf = gact[tid + 128];
            float gg = gact[tid + 256], go = gact[tid + 384];
            c1 = fmaf(gf, c1, gi * gg);
            float h1 = go * tanhf_(c1);
            ((uint16_t*)h1p)[tid] = f2h(h1);
        }
        __syncthreads();   // barrier 2

        // ---------- phase 2a: W_ih2 . h1_new (register weights)
        float pA = bias2, pB = 0.f;
        DOT_Q(w2a, Hv1, 0, pA); DOT_Q(w2b, Hv1, 1, pB); SB();
        DOT_Q(w2c, Hv1, 2, pA); DOT_Q(w2d, Hv1, 3, pB); SB();

        // ---------- phase 2b: W_hh2 . h2_old (LDS weights, pipelined)
        // Double-buffered: load quarter q+1 while dotting quarter q.
        // Live temps: 16 uint4 = 64 dwords, fenced by SB().
        uint4 U0, U1, U2, U3, V0, V1, V2, V3;
        uint4 P0, P1, P2, P3, Q0, Q1, Q2, Q3;
        float qA = 0.f, qB = 0.f;
        LOADW(U0, U1, U2, U3, Wv, wbase, 0); LOADH(P0, P1, P2, P3, Hv2, 0); SB();
        LOADW(V0, V1, V2, V3, Wv, wbase, 1); LOADH(Q0, Q1, Q2, Q3, Hv2, 1);
        DOTW(U0, U1, U2, U3, P0, P1, P2, P3, pA, pB); SB();
        LOADW(U0, U1, U2, U3, Wv, wbase, 2); LOADH(P0, P1, P2, P3, Hv2, 2);
        DOTW(V0, V1, V2, V3, Q0, Q1, Q2, Q3, qA, qB); SB();
        LOADW(V0, V1, V2, V3, Wv, wbase, 3); LOADH(Q0, Q1, Q2, Q3, Hv2, 3);
        DOTW(U0, U1, U2, U3, P0, P1, P2, P3, pA, pB); SB();
        DOTW(V0, V1, V2, V3, Q0, Q1, Q2, Q3, qA, qB);

        float g2 = (pA + pB) + (qA + qB);
        gact[tid] = (sec == 2) ? tanhf_(g2) : sigmoidf_(g2);
        __syncthreads();   // barrier 3

        // ---------- layer-2 state update
        if (tid < HDIM) {
            float gi = gact[tid], gf = gact[tid + 128];
            float gg = gact[tid + 256], go = gact[tid + 384];
            c2 = fmaf(gf, c2, gi * gg);
            float h2 = go * tanhf_(c2);
            ((uint16_t*)h2p)[tid] = f2h(h2);
            h2f[tid] = h2;
        }
        __syncthreads();   // barrier 4

        // ---------- output: out[b,t] = W_out . h2 + b_out   (wave 0 only)
        if (tid < 64) {
            float p = fmaf(wo0, h2f[tid], wo1 * h2f[tid + 64]);
#pragma unroll
            for (int off = 32; off > 0; off >>= 1)
                p += __shfl_down(p, off, 64);
            if (tid == 0) ob[t] = p + bo;
        }
        x_cur = x_nxt;
    }
}

extern "C" void kernel_launch(void* const* d_in, const int* in_sizes, int n_in,
                              void* d_out, int out_size, void* d_ws, size_t ws_size,
                              hipStream_t stream) {
    const float* x     = (const float*)d_in[0];
    const float* W_ih1 = (const float*)d_in[1];
    const float* W_hh1 = (const float*)d_in[2];
    const float* b_ih1 = (const float*)d_in[3];
    const float* b_hh1 = (const float*)d_in[4];
    const float* W_ih2 = (const float*)d_in[5];
    const float* W_hh2 = (const float*)d_in[6];
    const float* b_ih2 = (const float*)d_in[7];
    const float* b_hh2 = (const float*)d_in[8];
    const float* W_out = (const float*)d_in[9];
    const float* b_out = (const float*)d_in[10];
    float* out = (float*)d_out;

    const int B = in_sizes[0] / T_STEPS;   // 256
    hipLaunchKernelGGL(lstm_persistent, dim3(B), dim3(NT), 0, stream,
                       x, W_ih1, W_hh1, b_ih1, b_hh1,
                       W_ih2, W_hh2, b_ih2, b_hh2, W_out, b_out, out);
}